// Round 17
// baseline (101.886 us; speedup 1.0000x reference)
//
#include <hip/hip_runtime.h>
#include <cmath>

// FusionLoss = ms_ssim(fus,ir)+ms_ssim(fus,vi) + l1(max(map_ir,map_vi),fus)
//            + 10*mean(|max(|lap ir|,|lap vi|) - |lap fus||)
// Inputs: im_fus, im_ir, im_vi, map_ir, map_vi  each [32,1,512,512] fp32.
//
// d_ws layout (floats): [0..2048) ssim | [2048..4096) l1 | [4096..6144) grad
//
// Journal: r2 atomics->partials. r9 pk-f32 (72.9us ssim). r14 lapl rides
// ssim pipeline (103.8 total). r15 DS/reg diet (96.5). r16 pair-row: 90.0,
// VGPR 112, VALU/DS both ~50%, occ 17.5% — latency-bound at 12 waves/CU.
// 256-thread blocks never fit 4/CU (r10/r13) even at VGPR<=112, though the
// VGPR bracket (65-128 -> 4 waves/SIMD) allows 16 waves/CU. r17 HYPOTHESIS:
// residency cap is BLOCK-granular. Test: 128-thread (2-wave) blocks, grid
// (4,16,32)=2048 = 8 blocks/CU = 16 waves/CU target. Kernel body = r16
// modulo geometry (32-row strips, lap bound 32, rb in {0,22}).
// GUARDS: VGPR<=128 (expect ~112), WRITE<=50KB. If occ stays ~17% ->
// 12 waves/CU is a hard ceiling; declare structural limit.

typedef float f32x2 __attribute__((ext_vector_type(2)));

struct GaussW { float w[11]; };

#define SSIM_C1 1.0e-4f
#define SSIM_C2 9.0e-4f

// ---------------- fused SSIM + L1 + laplacian kernel ------------------------
// Grid: (4 col blocks of 128, 16 row strips of 32, 32 batch) = 2048 blocks
// of 128 threads (2 waves). Wave wv owns 64 cols; wave-private LDS rows;
// no __syncthreads in the main loop (in-order DS pipe within a wave;
// wave_barrier() fences compiler reordering).
// Pair-row processing: rows r,r+1 staged together; 44 tap reads issued as
// one stream (one exposed-latency window per PAIR); two h-sum chains.
// Vertical gaussian: 11-slot ring; slot (row mod 11) OVERWRITTEN at k=0.
// Laplacian rides the sweep: 3-deep colsum history; strip rs owns lapl rows
// [32rs+1, 32rs+32]; strip 0 adds y=0 (reflect); strip 15 ends 510 + epi 511.
__global__ __launch_bounds__(128, 2)
void ssim_kernel(const float* __restrict__ fus, const float* __restrict__ irp,
                 const float* __restrict__ vip, const float* __restrict__ mir,
                 const float* __restrict__ mvi, float* __restrict__ ws,
                 GaussW gw)
{
    const int b    = blockIdx.z;
    const int rs   = blockIdx.y;
    const int r0   = rs * 32;
    const int tid  = threadIdx.x;
    const int wv   = tid >> 6;          // wave 0..1
    const int lane = tid & 63;
    const int c0   = blockIdx.x * 128 + wv * 64;   // wave's column base
    const int out_rows = min(32, 502 - r0);        // last strip: 22
    const int in_rows  = out_rows + 10;            // 42 or 32 (always even)
    const bool first = (rs == 0);
    const bool last  = (rs == 15);

    const size_t ib = (size_t)b * 512 * 512;
    const float* __restrict__ Fp = fus + ib;
    const float* __restrict__ Ip = irp + ib;
    const float* __restrict__ Vp = vip + ib;
    mir += ib;
    mvi += ib;

    __shared__ f32x2 srow_fi[2][2][80]; // [wave][row-of-pair][col]
    __shared__ float srow_v [2][2][80];

    float w6[6];                        // gaussian symmetric: w[k]=w[10-k]
#pragma unroll
    for (int k = 0; k < 6; ++k) w6[k] = gw.w[k];

    f32x2 acc[11][4];                   // ring: [0]={hf,hi} [1]={hff,hii} [2]={hfi,hfv} [3]={hv,hvv}
#pragma unroll
    for (int s = 0; s < 11; ++s)
#pragma unroll
        for (int q = 0; q < 4; ++q) acc[s][q] = (f32x2)(0.f);

    float lssim = 0.f, l1s = 0.f, grs = 0.f;
    const int  col      = c0 + lane;
    const bool col_ok   = col <= 501;             // ssim-valid output column
    // unified halo loader: lanes 0..9 -> right halo, lane 10 -> left halo (idx 74)
    const bool is_left  = (lane == 10);
    const int  colH     = is_left ? (c0 - 1) : (c0 + 64 + lane);
    const bool halo_ok  = (lane < 10) ? (colH < 512) : (is_left && c0 > 0);
    const int  hidx     = 64 + lane;              // lane10 -> 74
    // lapl neighbor LDS index (reflect at image edges)
    const int il       = (lane == 0) ? ((c0 == 0) ? 1 : 74) : (lane - 1);
    const bool rt_edge = (lane == 63) && (c0 + 64 >= 512);  // col 511: right=reflect=left

    // laplacian history (column sums of the 2 previous rows; center of prev row)
    f32x2 csFI_1 = (f32x2)(0.f), csFI_2 = (f32x2)(0.f);
    float csV_1 = 0.f, csV_2 = 0.f;
    f32x2 cPrevFI = (f32x2)(0.f); float cPrevV = 0.f;
    // mir/mvi prefetch: mA = row r0+r-1 (for y1), mB = row r0+r (for y2)
    float mA1 = 0.f, mA2 = 0.f, mB1, mB2;

    // prologue: prefetch rows 0 (A) and 1 (B), main + unified halo; mB = row r0
    float arf, arg, arv, arf2 = 0.f, arg2 = 0.f, arv2 = 0.f;
    float brf, brg, brv, brf2 = 0.f, brg2 = 0.f, brv2 = 0.f;
    {
        const size_t b0 = (size_t)r0 * 512 + col;
        arf = Fp[b0]; arg = Ip[b0]; arv = Vp[b0];
        const size_t b1 = (size_t)(r0 + 1) * 512 + col;
        brf = Fp[b1]; brg = Ip[b1]; brv = Vp[b1];
        if (halo_ok) {
            const size_t h0 = (size_t)r0 * 512 + colH;
            arf2 = Fp[h0]; arg2 = Ip[h0]; arv2 = Vp[h0];
            const size_t h1 = (size_t)(r0 + 1) * 512 + colH;
            brf2 = Fp[h1]; brg2 = Ip[h1]; brv2 = Vp[h1];
        }
        mB1 = mir[b0]; mB2 = mvi[b0];
    }

#pragma unroll 1
    for (int rb = 0; rb < 44; rb += 22) {   // rb in {0,22}; 22%11==0 keeps slots static
#pragma unroll
        for (int p = 0; p < 11; ++p) {
            const int r = rb + 2 * p;             // even row of the pair
            if (r < in_rows) {                    // wave-uniform; covers r+1 too
                // stage both rows (b64 pair + b32 V each, + unified halo)
                srow_fi[wv][0][lane] = (f32x2){arf, arg};
                srow_v [wv][0][lane] = arv;
                srow_fi[wv][1][lane] = (f32x2){brf, brg};
                srow_v [wv][1][lane] = brv;
                if (halo_ok) {
                    srow_fi[wv][0][hidx] = (f32x2){arf2, arg2};
                    srow_v [wv][0][hidx] = arv2;
                    srow_fi[wv][1][hidx] = (f32x2){brf2, brg2};
                    srow_v [wv][1][hidx] = brv2;
                }
                __builtin_amdgcn_wave_barrier();  // fence write->read order

                // prefetch rows r+2 (A) and r+3 (B); consumed next pair
                if (r + 2 < in_rows) {
                    const size_t bA = (size_t)(r0 + r + 2) * 512 + col;
                    arf = Fp[bA]; arg = Ip[bA]; arv = Vp[bA];
                    const size_t bB = (size_t)(r0 + r + 3) * 512 + col;
                    brf = Fp[bB]; brg = Ip[bB]; brv = Vp[bB];
                    if (halo_ok) {
                        const size_t hA = (size_t)(r0 + r + 2) * 512 + colH;
                        arf2 = Fp[hA]; arg2 = Ip[hA]; arv2 = Vp[hA];
                        const size_t hB = (size_t)(r0 + r + 3) * 512 + colH;
                        brf2 = Fp[hB]; brg2 = Ip[hB]; brv2 = Vp[hB];
                    }
                }

                // horizontal gaussian sums for BOTH rows (one read stream,
                // two independent dependency chains); capture k=0 (center)
                // and k=1 (right neighbor) taps for the laplacian.
                f32x2 hfhiA = (f32x2)(0.f), hffiiA = (f32x2)(0.f);
                f32x2 hfifvA = (f32x2)(0.f), hvvvA = (f32x2)(0.f);
                f32x2 hfhiB = (f32x2)(0.f), hffiiB = (f32x2)(0.f);
                f32x2 hfifvB = (f32x2)(0.f), hvvvB = (f32x2)(0.f);
                f32x2 fi0A = (f32x2)(0.f), fi1A = (f32x2)(0.f);
                f32x2 fi0B = (f32x2)(0.f), fi1B = (f32x2)(0.f);
                float v0A = 0.f, v1A = 0.f, v0B = 0.f, v1B = 0.f;
#pragma unroll
                for (int k = 0; k < 11; ++k) {
                    const float t = w6[k < 6 ? k : 10 - k];
                    const f32x2 t2 = (f32x2){t, t};
                    const f32x2 fiA = srow_fi[wv][0][lane + k];
                    const float VA  = srow_v [wv][0][lane + k];
                    const f32x2 fiB = srow_fi[wv][1][lane + k];
                    const float VB  = srow_v [wv][1][lane + k];
                    if (k == 0) { fi0A = fiA; v0A = VA; fi0B = fiB; v0B = VB; }
                    if (k == 1) { fi1A = fiA; v1A = VA; fi1B = fiB; v1B = VB; }
                    const f32x2 tfiA = t2 * fiA;
                    hfhiA  = __builtin_elementwise_fma(t2,   fiA, hfhiA);
                    hffiiA = __builtin_elementwise_fma(tfiA, fiA, hffiiA);
                    hfifvA.x = fmaf(tfiA.x, fiA.y, hfifvA.x);
                    hfifvA.y = fmaf(tfiA.x, VA,    hfifvA.y);
                    hvvvA.x = fmaf(t,      VA, hvvvA.x);
                    hvvvA.y = fmaf(t * VA, VA, hvvvA.y);
                    const f32x2 tfiB = t2 * fiB;
                    hfhiB  = __builtin_elementwise_fma(t2,   fiB, hfhiB);
                    hffiiB = __builtin_elementwise_fma(tfiB, fiB, hffiiB);
                    hfifvB.x = fmaf(tfiB.x, fiB.y, hfifvB.x);
                    hfifvB.y = fmaf(tfiB.x, VB,    hfifvB.y);
                    hvvvB.x = fmaf(t,      VB, hvvvB.x);
                    hvvvB.y = fmaf(t * VB, VB, hvvvB.y);
                }

                // lapl column sums for both rows (left from LDS, right = k=1 tap)
                const bool lap = (r <= 32) || last;
                f32x2 csA_FI = (f32x2)(0.f), csB_FI = (f32x2)(0.f);
                float csA_V = 0.f, csB_V = 0.f;
                if (lap) {
                    const f32x2 fiLA = srow_fi[wv][0][il];
                    const float vLA  = srow_v [wv][0][il];
                    const f32x2 fiLB = srow_fi[wv][1][il];
                    const float vLB  = srow_v [wv][1][il];
                    f32x2 fiRA = fi1A; float vRA = v1A;
                    f32x2 fiRB = fi1B; float vRB = v1B;
                    if (rt_edge) { fiRA = fiLA; vRA = vLA; fiRB = fiLB; vRB = vLB; }
                    csA_FI = fiLA + fiRA + fi0A;  csA_V = vLA + vRA + v0A;
                    csB_FI = fiLB + fiRB + fi0B;  csB_V = vLB + vRB + v0B;
                }
                __builtin_amdgcn_wave_barrier();  // fence read->next-write

                // ---- row r: ring update then finalize output r-10 ----
                {
                    const f32x2 w02 = (f32x2){w6[0], w6[0]};
                    acc[(2*p) % 11][0] = w02 * hfhiA;
                    acc[(2*p) % 11][1] = w02 * hffiiA;
                    acc[(2*p) % 11][2] = w02 * hfifvA;
                    acc[(2*p) % 11][3] = w02 * hvvvA;
                }
#pragma unroll
                for (int k = 1; k < 11; ++k) {
                    const int s = (2*p - k + 22) % 11;   // compile-time
                    const float t = w6[k < 6 ? k : 10 - k];
                    const f32x2 t2 = (f32x2){t, t};
                    acc[s][0] = __builtin_elementwise_fma(t2, hfhiA,  acc[s][0]);
                    acc[s][1] = __builtin_elementwise_fma(t2, hffiiA, acc[s][1]);
                    acc[s][2] = __builtin_elementwise_fma(t2, hfifvA, acc[s][2]);
                    acc[s][3] = __builtin_elementwise_fma(t2, hvvvA,  acc[s][3]);
                }
                if (r >= 10) {
                    const int s = (2*p + 1) % 11;        // compile-time
                    const float mu1 = acc[s][0].x, mu2 = acc[s][0].y, mu3 = acc[s][3].x;
                    const float eff = acc[s][1].x, eii = acc[s][1].y, evv = acc[s][3].y;
                    const float efi = acc[s][2].x, efv = acc[s][2].y;
                    const float mu1sq = mu1*mu1, mu2sq = mu2*mu2, mu3sq = mu3*mu3;
                    const float mu12 = mu1*mu2, mu13 = mu1*mu3;
                    const float sf  = eff - mu1sq;
                    const float si  = eii - mu2sq;
                    const float sv  = evv - mu3sq;
                    const float s12 = efi - mu12;
                    const float s13 = efv - mu13;
                    const float n1 = (2.f*mu12 + SSIM_C1) * (2.f*s12 + SSIM_C2);
                    const float d1 = (mu1sq + mu2sq + SSIM_C1) * (sf + si + SSIM_C2);
                    const float n2 = (2.f*mu13 + SSIM_C1) * (2.f*s13 + SSIM_C2);
                    const float d2 = (mu1sq + mu3sq + SSIM_C1) * (sf + sv + SSIM_C2);
                    const float q1 = __builtin_amdgcn_rcpf(d1);   // ~2^-22 vs 6.6e-2 tol
                    const float q2 = __builtin_amdgcn_rcpf(d2);
                    if (col_ok) lssim += fmaf(n1, q1, n2 * q2);
                }
                // ---- row r+1: ring update then finalize output r-9 ----
                {
                    const f32x2 w02 = (f32x2){w6[0], w6[0]};
                    acc[(2*p + 1) % 11][0] = w02 * hfhiB;
                    acc[(2*p + 1) % 11][1] = w02 * hffiiB;
                    acc[(2*p + 1) % 11][2] = w02 * hfifvB;
                    acc[(2*p + 1) % 11][3] = w02 * hvvvB;
                }
#pragma unroll
                for (int k = 1; k < 11; ++k) {
                    const int s = (2*p + 1 - k + 22) % 11;   // compile-time
                    const float t = w6[k < 6 ? k : 10 - k];
                    const f32x2 t2 = (f32x2){t, t};
                    acc[s][0] = __builtin_elementwise_fma(t2, hfhiB,  acc[s][0]);
                    acc[s][1] = __builtin_elementwise_fma(t2, hffiiB, acc[s][1]);
                    acc[s][2] = __builtin_elementwise_fma(t2, hfifvB, acc[s][2]);
                    acc[s][3] = __builtin_elementwise_fma(t2, hvvvB,  acc[s][3]);
                }
                if (r >= 10) {
                    const int s = (2*p + 2) % 11;        // compile-time
                    const float mu1 = acc[s][0].x, mu2 = acc[s][0].y, mu3 = acc[s][3].x;
                    const float eff = acc[s][1].x, eii = acc[s][1].y, evv = acc[s][3].y;
                    const float efi = acc[s][2].x, efv = acc[s][2].y;
                    const float mu1sq = mu1*mu1, mu2sq = mu2*mu2, mu3sq = mu3*mu3;
                    const float mu12 = mu1*mu2, mu13 = mu1*mu3;
                    const float sf  = eff - mu1sq;
                    const float si  = eii - mu2sq;
                    const float sv  = evv - mu3sq;
                    const float s12 = efi - mu12;
                    const float s13 = efv - mu13;
                    const float n1 = (2.f*mu12 + SSIM_C1) * (2.f*s12 + SSIM_C2);
                    const float d1 = (mu1sq + mu2sq + SSIM_C1) * (sf + si + SSIM_C2);
                    const float n2 = (2.f*mu13 + SSIM_C1) * (2.f*s13 + SSIM_C2);
                    const float d2 = (mu1sq + mu3sq + SSIM_C1) * (sf + sv + SSIM_C2);
                    const float q1 = __builtin_amdgcn_rcpf(d1);
                    const float q2 = __builtin_amdgcn_rcpf(d2);
                    if (col_ok) lssim += fmaf(n1, q1, n2 * q2);
                }

                // ---- laplacian + l1 emissions (16x-unscaled lapl) ----
                if (lap) {
                    if (r >= 2) {
                        // y1 = r0+r-1: rows r-2, r-1, r; center row r-1
                        const f32x2 sFI = csFI_2 + csFI_1 + csA_FI;
                        const float sV  = csV_2 + csV_1 + csA_V;
                        const f32x2 lFI = __builtin_elementwise_fma(
                                             (f32x2){-9.f,-9.f}, cPrevFI, sFI);
                        const float lV  = fmaf(-9.f, cPrevV, sV);
                        grs += fabsf(fmaxf(fabsf(lFI.y), fabsf(lV)) - fabsf(lFI.x));
                        l1s += fabsf(fmaxf(mA1, mA2) - cPrevFI.x);
                        // y2 = r0+r: rows r-1, r, r+1; center row r
                        const f32x2 sFI2 = csFI_1 + csA_FI + csB_FI;
                        const float sV2  = csV_1 + csA_V + csB_V;
                        const f32x2 lFI2 = __builtin_elementwise_fma(
                                             (f32x2){-9.f,-9.f}, fi0A, sFI2);
                        const float lV2  = fmaf(-9.f, v0A, sV2);
                        grs += fabsf(fmaxf(fabsf(lFI2.y), fabsf(lV2)) - fabsf(lFI2.x));
                        l1s += fabsf(fmaxf(mB1, mB2) - fi0A.x);
                    }
                    if (first && r == 0) {
                        // y = 0: rows reflect(-1)=1, 0, 1; center row 0
                        const f32x2 sFI = csA_FI + csB_FI + csB_FI;
                        const float sV  = csA_V + csB_V + csB_V;
                        const f32x2 lFI = __builtin_elementwise_fma(
                                             (f32x2){-9.f,-9.f}, fi0A, sFI);
                        const float lV  = fmaf(-9.f, v0A, sV);
                        grs += fabsf(fmaxf(fabsf(lFI.y), fabsf(lV)) - fabsf(lFI.x));
                        l1s += fabsf(fmaxf(mB1, mB2) - fi0A.x);
                    }
                    // shift history by 2 rows; prefetch m rows for next pair
                    csFI_2 = csA_FI; csFI_1 = csB_FI;
                    csV_2  = csA_V;  csV_1  = csB_V;
                    cPrevFI = fi0B;  cPrevV = v0B;
                    if (r + 2 < in_rows) {
                        const int yA = min(r0 + r + 1, 511);
                        const int yB = min(r0 + r + 2, 511);
                        const size_t bmA = (size_t)yA * 512 + col;
                        const size_t bmB = (size_t)yB * 512 + col;
                        mA1 = mir[bmA]; mA2 = mvi[bmA];
                        mB1 = mir[bmB]; mB2 = mvi[bmB];
                    }
                }
            }
        }
    }

    // epilogue: last strip handles row 511 (reflect row 512 -> 510)
    if (last) {
        const size_t bm = (size_t)511 * 512 + col;
        const float m1e = mir[bm], m2e = mvi[bm];
        const f32x2 sFI = csFI_2 + csFI_2 + csFI_1;
        const float sV  = csV_2 + csV_2 + csV_1;
        const f32x2 lFI = __builtin_elementwise_fma((f32x2){-9.f,-9.f}, cPrevFI, sFI);
        const float lV  = fmaf(-9.f, cPrevV, sV);
        grs += fabsf(fmaxf(fabsf(lFI.y), fabsf(lV)) - fabsf(lFI.x));
        l1s += fabsf(fmaxf(m1e, m2e) - cPrevFI.x);
    }

    // cross-wave block reduction -> three partial writes (no atomics)
#pragma unroll
    for (int off = 32; off > 0; off >>= 1) {
        lssim += __shfl_down(lssim, off);
        l1s   += __shfl_down(l1s, off);
        grs   += __shfl_down(grs, off);
    }
    __shared__ float red[6];
    if (lane == 0) { red[wv] = lssim; red[2 + wv] = l1s; red[4 + wv] = grs; }
    __syncthreads();
    if (tid == 0) {
        const int blk = blockIdx.x + 4 * (blockIdx.y + 16 * blockIdx.z); // 0..2047
        ws[blk]        = red[0] + red[1];
        ws[2048 + blk] = red[2] + red[3];
        ws[4096 + blk] = (red[4] + red[5]) * 0.0625f;   // fold 1/16
    }
}

// ---------------- final combine: reduce all partials ------------------------
__global__ void final_kernel(const float* __restrict__ ws, float* __restrict__ out)
{
    const int tid = threadIdx.x;
    float s0 = 0.f, s1 = 0.f, s2 = 0.f;
#pragma unroll
    for (int i = tid; i < 2048; i += 256) {
        s0 += ws[i];
        s1 += ws[2048 + i];
        s2 += ws[4096 + i];
    }
#pragma unroll
    for (int off = 32; off > 0; off >>= 1) {
        s0 += __shfl_down(s0, off);
        s1 += __shfl_down(s1, off);
        s2 += __shfl_down(s2, off);
    }
    __shared__ float red[12];
    if ((tid & 63) == 0) {
        red[tid >> 6] = s0; red[4 + (tid >> 6)] = s1; red[8 + (tid >> 6)] = s2;
    }
    __syncthreads();
    if (tid == 0) {
        const float ssim_sum = red[0] + red[1] + red[2] + red[3];
        const float l1_sum   = red[4] + red[5] + red[6] + red[7];
        const float gr_sum   = red[8] + red[9] + red[10] + red[11];
        const float ms = 2.f - ssim_sum / 8064128.f;   // 32*502*502
        const float l1 = l1_sum / 8388608.f;           // 32*512*512
        const float gr = gr_sum / 8388608.f;
        out[0] = ms + l1 + 10.f * gr;
    }
}

extern "C" void kernel_launch(void* const* d_in, const int* in_sizes, int n_in,
                              void* d_out, int out_size, void* d_ws, size_t ws_size,
                              hipStream_t stream)
{
    const float* fus = (const float*)d_in[0];
    const float* irp = (const float*)d_in[1];
    const float* vip = (const float*)d_in[2];
    const float* mir = (const float*)d_in[3];
    const float* mvi = (const float*)d_in[4];
    float* out = (float*)d_out;
    float* ws  = (float*)d_ws;

    // gaussian window (matches np: f64 normalize, cast to f32)
    GaussW gw;
    double g[11], s = 0.0;
    for (int i = 0; i < 11; ++i) {
        const double d = (double)i - 5.0;
        g[i] = std::exp(-(d * d) / (2.0 * 1.5 * 1.5));
        s += g[i];
    }
    for (int i = 0; i < 11; ++i) gw.w[i] = (float)(g[i] / s);

    ssim_kernel<<<dim3(4, 16, 32), 128, 0, stream>>>(fus, irp, vip, mir, mvi,
                                                     ws, gw);
    final_kernel<<<1, 256, 0, stream>>>(ws, out);
}

// Round 18
// 101.592 us; speedup vs baseline: 1.0029x; 1.0029x over previous
//
#include <hip/hip_runtime.h>
#include <cmath>

// FusionLoss = ms_ssim(fus,ir)+ms_ssim(fus,vi) + l1(max(map_ir,map_vi),fus)
//            + 10*mean(|max(|lap ir|,|lap vi|) - |lap fus||)
// Inputs: im_fus, im_ir, im_vi, map_ir, map_vi  each [32,1,512,512] fp32.
//
// d_ws layout (floats): [0..768) ssim | [768..1536) l1 | [1536..2304) grad
//
// Journal: r2 atomics->partials. r9 pk-f32. r14 lapl rides ssim pipeline.
// r15 DS diet (96.5). r16 pair-row BEST: 90.0us, VGPR 112, both pipes ~50%.
// r17 REFUTED block-granularity: 2-wave blocks -> occ still 17%, 101.9us.
// Occupancy levers exhausted (r10/r13/r17). r18: cut DS instr count —
// float4 LDS rows {F,I,V,F*V}: 1 b128/tap replaces b64+b32 (22->11
// reads/row), 1 b128 write replaces 2, 1 b128 lapl read replaces 2.
// DS/row ~26 -> ~14. r8's b128 failure was at VGPR cap 85 (lb 256,3);
// r16 runs under cap 128 (lb 256,2) with headroom for the quads.
// GUARDS: VGPR<=128 (no scratch), WRITE<=50KB else revert to r16.

typedef float f32x2 __attribute__((ext_vector_type(2)));

struct GaussW { float w[11]; };

#define SSIM_C1 1.0e-4f
#define SSIM_C2 9.0e-4f

// ---------------- fused SSIM + L1 + laplacian kernel ------------------------
// Grid: (2 col blocks of 256, 12 row strips of 42, 32 batch) = 768 blocks.
// Block = 4 independent waves; wave wv owns 64 cols; wave-private LDS rows;
// no __syncthreads in the main loop (in-order DS pipe within a wave;
// wave_barrier() fences compiler reordering).
// Pair-row processing: rows r,r+1 staged together; 22 b128 tap reads issued
// as one stream (one exposed-latency window per PAIR); two h-sum chains.
// Vertical gaussian: 11-slot ring; slot (row mod 11) OVERWRITTEN at k=0.
// Laplacian rides the sweep: 3-deep colsum history; strip rs owns lapl rows
// [42rs+1, 42rs+42]; strip 0 adds y=0 (reflect); strip 11 ends 510 + epi 511.
__global__ __launch_bounds__(256, 2)
void ssim_kernel(const float* __restrict__ fus, const float* __restrict__ irp,
                 const float* __restrict__ vip, const float* __restrict__ mir,
                 const float* __restrict__ mvi, float* __restrict__ ws,
                 GaussW gw)
{
    const int b    = blockIdx.z;
    const int rs   = blockIdx.y;
    const int r0   = rs * 42;
    const int tid  = threadIdx.x;
    const int wv   = tid >> 6;          // wave 0..3
    const int lane = tid & 63;
    const int c0   = blockIdx.x * 256 + wv * 64;   // wave's column base
    const int out_rows = min(42, 502 - r0);        // last strip: 40
    const int in_rows  = out_rows + 10;            // 52 or 50 (always even)
    const bool first = (rs == 0);
    const bool last  = (rs == 11);

    const size_t ib = (size_t)b * 512 * 512;
    const float* __restrict__ Fp = fus + ib;
    const float* __restrict__ Ip = irp + ib;
    const float* __restrict__ Vp = vip + ib;
    mir += ib;
    mvi += ib;

    __shared__ float4 srow[4][2][80];   // [wave][row-of-pair][col] = {F,I,V,F*V}

    float w6[6];                        // gaussian symmetric: w[k]=w[10-k]
#pragma unroll
    for (int k = 0; k < 6; ++k) w6[k] = gw.w[k];

    f32x2 acc[11][4];                   // ring: [0]={hf,hi} [1]={hff,hii} [2]={hfi,hfv} [3]={hv,hvv}
#pragma unroll
    for (int s = 0; s < 11; ++s)
#pragma unroll
        for (int q = 0; q < 4; ++q) acc[s][q] = (f32x2)(0.f);

    float lssim = 0.f, l1s = 0.f, grs = 0.f;
    const int  col      = c0 + lane;
    const bool col_ok   = col <= 501;             // ssim-valid output column
    // unified halo loader: lanes 0..9 -> right halo, lane 10 -> left halo (idx 74)
    const bool is_left  = (lane == 10);
    const int  colH     = is_left ? (c0 - 1) : (c0 + 64 + lane);
    const bool halo_ok  = (lane < 10) ? (colH < 512) : (is_left && c0 > 0);
    const int  hidx     = 64 + lane;              // lane10 -> 74
    // lapl neighbor LDS index (reflect at image edges)
    const int il       = (lane == 0) ? ((c0 == 0) ? 1 : 74) : (lane - 1);
    const bool rt_edge = (lane == 63) && (c0 + 64 >= 512);  // col 511: right=reflect=left

    // laplacian history (column sums of the 2 previous rows; center of prev row)
    f32x2 csFI_1 = (f32x2)(0.f), csFI_2 = (f32x2)(0.f);
    float csV_1 = 0.f, csV_2 = 0.f;
    f32x2 cPrevFI = (f32x2)(0.f); float cPrevV = 0.f;
    // mir/mvi prefetch: mA = row r0+r-1 (for y1), mB = row r0+r (for y2)
    float mA1 = 0.f, mA2 = 0.f, mB1, mB2;

    // prologue: prefetch rows 0 (A) and 1 (B), main + unified halo; mB = row r0
    float arf, arg, arv, arf2 = 0.f, arg2 = 0.f, arv2 = 0.f;
    float brf, brg, brv, brf2 = 0.f, brg2 = 0.f, brv2 = 0.f;
    {
        const size_t b0 = (size_t)r0 * 512 + col;
        arf = Fp[b0]; arg = Ip[b0]; arv = Vp[b0];
        const size_t b1 = (size_t)(r0 + 1) * 512 + col;
        brf = Fp[b1]; brg = Ip[b1]; brv = Vp[b1];
        if (halo_ok) {
            const size_t h0 = (size_t)r0 * 512 + colH;
            arf2 = Fp[h0]; arg2 = Ip[h0]; arv2 = Vp[h0];
            const size_t h1 = (size_t)(r0 + 1) * 512 + colH;
            brf2 = Fp[h1]; brg2 = Ip[h1]; brv2 = Vp[h1];
        }
        mB1 = mir[b0]; mB2 = mvi[b0];
    }

#pragma unroll 1
    for (int rb = 0; rb < 66; rb += 22) {
#pragma unroll
        for (int p = 0; p < 11; ++p) {
            const int r = rb + 2 * p;             // even row of the pair
            if (r < in_rows) {                    // wave-uniform; covers r+1 too
                // stage both rows: ONE ds_write_b128 each (+ halo)
                srow[wv][0][lane] = make_float4(arf, arg, arv, arf * arv);
                srow[wv][1][lane] = make_float4(brf, brg, brv, brf * brv);
                if (halo_ok) {
                    srow[wv][0][hidx] = make_float4(arf2, arg2, arv2, arf2 * arv2);
                    srow[wv][1][hidx] = make_float4(brf2, brg2, brv2, brf2 * brv2);
                }
                __builtin_amdgcn_wave_barrier();  // fence write->read order

                // prefetch rows r+2 (A) and r+3 (B); consumed next pair
                if (r + 2 < in_rows) {
                    const size_t bA = (size_t)(r0 + r + 2) * 512 + col;
                    arf = Fp[bA]; arg = Ip[bA]; arv = Vp[bA];
                    const size_t bB = (size_t)(r0 + r + 3) * 512 + col;
                    brf = Fp[bB]; brg = Ip[bB]; brv = Vp[bB];
                    if (halo_ok) {
                        const size_t hA = (size_t)(r0 + r + 2) * 512 + colH;
                        arf2 = Fp[hA]; arg2 = Ip[hA]; arv2 = Vp[hA];
                        const size_t hB = (size_t)(r0 + r + 3) * 512 + colH;
                        brf2 = Fp[hB]; brg2 = Ip[hB]; brv2 = Vp[hB];
                    }
                }

                // horizontal gaussian sums for BOTH rows; ONE b128 read/tap.
                // capture k=0 (center) and k=1 (right neighbor) for the lapl.
                f32x2 hfhiA = (f32x2)(0.f), hffiiA = (f32x2)(0.f);
                f32x2 hfifvA = (f32x2)(0.f), hvvvA = (f32x2)(0.f);
                f32x2 hfhiB = (f32x2)(0.f), hffiiB = (f32x2)(0.f);
                f32x2 hfifvB = (f32x2)(0.f), hvvvB = (f32x2)(0.f);
                f32x2 fi0A = (f32x2)(0.f), fi1A = (f32x2)(0.f);
                f32x2 fi0B = (f32x2)(0.f), fi1B = (f32x2)(0.f);
                float v0A = 0.f, v1A = 0.f, v0B = 0.f, v1B = 0.f;
#pragma unroll
                for (int k = 0; k < 11; ++k) {
                    const float t = w6[k < 6 ? k : 10 - k];
                    const f32x2 t2 = (f32x2){t, t};
                    const float4 tA = srow[wv][0][lane + k];
                    const float4 tB = srow[wv][1][lane + k];
                    const f32x2 fiA = (f32x2){tA.x, tA.y};
                    const f32x2 fiB = (f32x2){tB.x, tB.y};
                    if (k == 0) { fi0A = fiA; v0A = tA.z; fi0B = fiB; v0B = tB.z; }
                    if (k == 1) { fi1A = fiA; v1A = tA.z; fi1B = fiB; v1B = tB.z; }
                    const f32x2 tfiA = t2 * fiA;
                    hfhiA  = __builtin_elementwise_fma(t2,   fiA, hfhiA);
                    hffiiA = __builtin_elementwise_fma(tfiA, fiA, hffiiA);
                    hfifvA.x = fmaf(tfiA.x, fiA.y, hfifvA.x);   // w*F*I
                    hfifvA.y = fmaf(t, tA.w, hfifvA.y);         // w*(F*V) stored
                    hvvvA.x = fmaf(t, tA.z, hvvvA.x);           // w*V
                    hvvvA.y = fmaf(t * tA.z, tA.z, hvvvA.y);    // w*V^2
                    const f32x2 tfiB = t2 * fiB;
                    hfhiB  = __builtin_elementwise_fma(t2,   fiB, hfhiB);
                    hffiiB = __builtin_elementwise_fma(tfiB, fiB, hffiiB);
                    hfifvB.x = fmaf(tfiB.x, fiB.y, hfifvB.x);
                    hfifvB.y = fmaf(t, tB.w, hfifvB.y);
                    hvvvB.x = fmaf(t, tB.z, hvvvB.x);
                    hvvvB.y = fmaf(t * tB.z, tB.z, hvvvB.y);
                }

                // lapl column sums for both rows (left = ONE b128 read; right = k=1 tap)
                const bool lap = (r <= 43) || last;
                f32x2 csA_FI = (f32x2)(0.f), csB_FI = (f32x2)(0.f);
                float csA_V = 0.f, csB_V = 0.f;
                if (lap) {
                    const float4 LA = srow[wv][0][il];
                    const float4 LB = srow[wv][1][il];
                    const f32x2 fiLA = (f32x2){LA.x, LA.y};
                    const f32x2 fiLB = (f32x2){LB.x, LB.y};
                    const float vLA = LA.z, vLB = LB.z;
                    f32x2 fiRA = fi1A; float vRA = v1A;
                    f32x2 fiRB = fi1B; float vRB = v1B;
                    if (rt_edge) { fiRA = fiLA; vRA = vLA; fiRB = fiLB; vRB = vLB; }
                    csA_FI = fiLA + fiRA + fi0A;  csA_V = vLA + vRA + v0A;
                    csB_FI = fiLB + fiRB + fi0B;  csB_V = vLB + vRB + v0B;
                }
                __builtin_amdgcn_wave_barrier();  // fence read->next-write

                // ---- row r: ring update then finalize output r-10 ----
                {
                    const f32x2 w02 = (f32x2){w6[0], w6[0]};
                    acc[(2*p) % 11][0] = w02 * hfhiA;
                    acc[(2*p) % 11][1] = w02 * hffiiA;
                    acc[(2*p) % 11][2] = w02 * hfifvA;
                    acc[(2*p) % 11][3] = w02 * hvvvA;
                }
#pragma unroll
                for (int k = 1; k < 11; ++k) {
                    const int s = (2*p - k + 22) % 11;   // compile-time
                    const float t = w6[k < 6 ? k : 10 - k];
                    const f32x2 t2 = (f32x2){t, t};
                    acc[s][0] = __builtin_elementwise_fma(t2, hfhiA,  acc[s][0]);
                    acc[s][1] = __builtin_elementwise_fma(t2, hffiiA, acc[s][1]);
                    acc[s][2] = __builtin_elementwise_fma(t2, hfifvA, acc[s][2]);
                    acc[s][3] = __builtin_elementwise_fma(t2, hvvvA,  acc[s][3]);
                }
                if (r >= 10) {
                    const int s = (2*p + 1) % 11;        // compile-time
                    const float mu1 = acc[s][0].x, mu2 = acc[s][0].y, mu3 = acc[s][3].x;
                    const float eff = acc[s][1].x, eii = acc[s][1].y, evv = acc[s][3].y;
                    const float efi = acc[s][2].x, efv = acc[s][2].y;
                    const float mu1sq = mu1*mu1, mu2sq = mu2*mu2, mu3sq = mu3*mu3;
                    const float mu12 = mu1*mu2, mu13 = mu1*mu3;
                    const float sf  = eff - mu1sq;
                    const float si  = eii - mu2sq;
                    const float sv  = evv - mu3sq;
                    const float s12 = efi - mu12;
                    const float s13 = efv - mu13;
                    const float n1 = (2.f*mu12 + SSIM_C1) * (2.f*s12 + SSIM_C2);
                    const float d1 = (mu1sq + mu2sq + SSIM_C1) * (sf + si + SSIM_C2);
                    const float n2 = (2.f*mu13 + SSIM_C1) * (2.f*s13 + SSIM_C2);
                    const float d2 = (mu1sq + mu3sq + SSIM_C1) * (sf + sv + SSIM_C2);
                    const float q1 = __builtin_amdgcn_rcpf(d1);   // ~2^-22 vs 6.6e-2 tol
                    const float q2 = __builtin_amdgcn_rcpf(d2);
                    if (col_ok) lssim += fmaf(n1, q1, n2 * q2);
                }
                // ---- row r+1: ring update then finalize output r-9 ----
                {
                    const f32x2 w02 = (f32x2){w6[0], w6[0]};
                    acc[(2*p + 1) % 11][0] = w02 * hfhiB;
                    acc[(2*p + 1) % 11][1] = w02 * hffiiB;
                    acc[(2*p + 1) % 11][2] = w02 * hfifvB;
                    acc[(2*p + 1) % 11][3] = w02 * hvvvB;
                }
#pragma unroll
                for (int k = 1; k < 11; ++k) {
                    const int s = (2*p + 1 - k + 22) % 11;   // compile-time
                    const float t = w6[k < 6 ? k : 10 - k];
                    const f32x2 t2 = (f32x2){t, t};
                    acc[s][0] = __builtin_elementwise_fma(t2, hfhiB,  acc[s][0]);
                    acc[s][1] = __builtin_elementwise_fma(t2, hffiiB, acc[s][1]);
                    acc[s][2] = __builtin_elementwise_fma(t2, hfifvB, acc[s][2]);
                    acc[s][3] = __builtin_elementwise_fma(t2, hvvvB,  acc[s][3]);
                }
                if (r >= 10) {
                    const int s = (2*p + 2) % 11;        // compile-time
                    const float mu1 = acc[s][0].x, mu2 = acc[s][0].y, mu3 = acc[s][3].x;
                    const float eff = acc[s][1].x, eii = acc[s][1].y, evv = acc[s][3].y;
                    const float efi = acc[s][2].x, efv = acc[s][2].y;
                    const float mu1sq = mu1*mu1, mu2sq = mu2*mu2, mu3sq = mu3*mu3;
                    const float mu12 = mu1*mu2, mu13 = mu1*mu3;
                    const float sf  = eff - mu1sq;
                    const float si  = eii - mu2sq;
                    const float sv  = evv - mu3sq;
                    const float s12 = efi - mu12;
                    const float s13 = efv - mu13;
                    const float n1 = (2.f*mu12 + SSIM_C1) * (2.f*s12 + SSIM_C2);
                    const float d1 = (mu1sq + mu2sq + SSIM_C1) * (sf + si + SSIM_C2);
                    const float n2 = (2.f*mu13 + SSIM_C1) * (2.f*s13 + SSIM_C2);
                    const float d2 = (mu1sq + mu3sq + SSIM_C1) * (sf + sv + SSIM_C2);
                    const float q1 = __builtin_amdgcn_rcpf(d1);
                    const float q2 = __builtin_amdgcn_rcpf(d2);
                    if (col_ok) lssim += fmaf(n1, q1, n2 * q2);
                }

                // ---- laplacian + l1 emissions (16x-unscaled lapl) ----
                if (lap) {
                    if (r >= 2) {
                        // y1 = r0+r-1: rows r-2, r-1, r; center row r-1
                        const f32x2 sFI = csFI_2 + csFI_1 + csA_FI;
                        const float sV  = csV_2 + csV_1 + csA_V;
                        const f32x2 lFI = __builtin_elementwise_fma(
                                             (f32x2){-9.f,-9.f}, cPrevFI, sFI);
                        const float lV  = fmaf(-9.f, cPrevV, sV);
                        grs += fabsf(fmaxf(fabsf(lFI.y), fabsf(lV)) - fabsf(lFI.x));
                        l1s += fabsf(fmaxf(mA1, mA2) - cPrevFI.x);
                        // y2 = r0+r: rows r-1, r, r+1; center row r
                        const f32x2 sFI2 = csFI_1 + csA_FI + csB_FI;
                        const float sV2  = csV_1 + csA_V + csB_V;
                        const f32x2 lFI2 = __builtin_elementwise_fma(
                                             (f32x2){-9.f,-9.f}, fi0A, sFI2);
                        const float lV2  = fmaf(-9.f, v0A, sV2);
                        grs += fabsf(fmaxf(fabsf(lFI2.y), fabsf(lV2)) - fabsf(lFI2.x));
                        l1s += fabsf(fmaxf(mB1, mB2) - fi0A.x);
                    }
                    if (first && r == 0) {
                        // y = 0: rows reflect(-1)=1, 0, 1; center row 0
                        const f32x2 sFI = csA_FI + csB_FI + csB_FI;
                        const float sV  = csA_V + csB_V + csB_V;
                        const f32x2 lFI = __builtin_elementwise_fma(
                                             (f32x2){-9.f,-9.f}, fi0A, sFI);
                        const float lV  = fmaf(-9.f, v0A, sV);
                        grs += fabsf(fmaxf(fabsf(lFI.y), fabsf(lV)) - fabsf(lFI.x));
                        l1s += fabsf(fmaxf(mB1, mB2) - fi0A.x);
                    }
                    // shift history by 2 rows; prefetch m rows for next pair
                    csFI_2 = csA_FI; csFI_1 = csB_FI;
                    csV_2  = csA_V;  csV_1  = csB_V;
                    cPrevFI = fi0B;  cPrevV = v0B;
                    if (r + 2 < in_rows) {
                        const int yA = min(r0 + r + 1, 511);
                        const int yB = min(r0 + r + 2, 511);
                        const size_t bmA = (size_t)yA * 512 + col;
                        const size_t bmB = (size_t)yB * 512 + col;
                        mA1 = mir[bmA]; mA2 = mvi[bmA];
                        mB1 = mir[bmB]; mB2 = mvi[bmB];
                    }
                }
            }
        }
    }

    // epilogue: last strip handles row 511 (reflect row 512 -> 510)
    if (last) {
        const size_t bm = (size_t)511 * 512 + col;
        const float m1e = mir[bm], m2e = mvi[bm];
        const f32x2 sFI = csFI_2 + csFI_2 + csFI_1;
        const float sV  = csV_2 + csV_2 + csV_1;
        const f32x2 lFI = __builtin_elementwise_fma((f32x2){-9.f,-9.f}, cPrevFI, sFI);
        const float lV  = fmaf(-9.f, cPrevV, sV);
        grs += fabsf(fmaxf(fabsf(lFI.y), fabsf(lV)) - fabsf(lFI.x));
        l1s += fabsf(fmaxf(m1e, m2e) - cPrevFI.x);
    }

    // cross-wave block reduction -> three partial writes (no atomics)
#pragma unroll
    for (int off = 32; off > 0; off >>= 1) {
        lssim += __shfl_down(lssim, off);
        l1s   += __shfl_down(l1s, off);
        grs   += __shfl_down(grs, off);
    }
    __shared__ float red[12];
    if (lane == 0) { red[wv] = lssim; red[4 + wv] = l1s; red[8 + wv] = grs; }
    __syncthreads();
    if (tid == 0) {
        const int blk = blockIdx.x + 2 * (blockIdx.y + 12 * blockIdx.z); // 0..767
        ws[blk]        = red[0] + red[1] + red[2] + red[3];
        ws[768 + blk]  = red[4] + red[5] + red[6] + red[7];
        ws[1536 + blk] = (red[8] + red[9] + red[10] + red[11]) * 0.0625f; // /16
    }
}

// ---------------- final combine: reduce all partials ------------------------
__global__ void final_kernel(const float* __restrict__ ws, float* __restrict__ out)
{
    const int tid = threadIdx.x;
    float s0 = 0.f, s1 = 0.f, s2 = 0.f;
#pragma unroll
    for (int i = tid; i < 768; i += 256) {
        s0 += ws[i];
        s1 += ws[768 + i];
        s2 += ws[1536 + i];
    }
#pragma unroll
    for (int off = 32; off > 0; off >>= 1) {
        s0 += __shfl_down(s0, off);
        s1 += __shfl_down(s1, off);
        s2 += __shfl_down(s2, off);
    }
    __shared__ float red[12];
    if ((tid & 63) == 0) {
        red[tid >> 6] = s0; red[4 + (tid >> 6)] = s1; red[8 + (tid >> 6)] = s2;
    }
    __syncthreads();
    if (tid == 0) {
        const float ssim_sum = red[0] + red[1] + red[2] + red[3];
        const float l1_sum   = red[4] + red[5] + red[6] + red[7];
        const float gr_sum   = red[8] + red[9] + red[10] + red[11];
        const float ms = 2.f - ssim_sum / 8064128.f;   // 32*502*502
        const float l1 = l1_sum / 8388608.f;           // 32*512*512
        const float gr = gr_sum / 8388608.f;
        out[0] = ms + l1 + 10.f * gr;
    }
}

extern "C" void kernel_launch(void* const* d_in, const int* in_sizes, int n_in,
                              void* d_out, int out_size, void* d_ws, size_t ws_size,
                              hipStream_t stream)
{
    const float* fus = (const float*)d_in[0];
    const float* irp = (const float*)d_in[1];
    const float* vip = (const float*)d_in[2];
    const float* mir = (const float*)d_in[3];
    const float* mvi = (const float*)d_in[4];
    float* out = (float*)d_out;
    float* ws  = (float*)d_ws;

    // gaussian window (matches np: f64 normalize, cast to f32)
    GaussW gw;
    double g[11], s = 0.0;
    for (int i = 0; i < 11; ++i) {
        const double d = (double)i - 5.0;
        g[i] = std::exp(-(d * d) / (2.0 * 1.5 * 1.5));
        s += g[i];
    }
    for (int i = 0; i < 11; ++i) gw.w[i] = (float)(g[i] / s);

    ssim_kernel<<<dim3(2, 12, 32), 256, 0, stream>>>(fus, irp, vip, mir, mvi,
                                                     ws, gw);
    final_kernel<<<1, 256, 0, stream>>>(ws, out);
}

// Round 19
// 91.655 us; speedup vs baseline: 1.1116x; 1.1084x over previous
//
#include <hip/hip_runtime.h>
#include <cmath>

// FusionLoss = ms_ssim(fus,ir)+ms_ssim(fus,vi) + l1(max(map_ir,map_vi),fus)
//            + 10*mean(|max(|lap ir|,|lap vi|) - |lap fus||)
// Inputs: im_fus, im_ir, im_vi, map_ir, map_vi  each [32,1,512,512] fp32.
//
// d_ws layout (floats): [0..768) ssim | [768..1536) l1 | [1536..2304) grad
//
// Journal: r16 BEST 90.0us (pair-row, VGPR 112). Refuted: occupancy levers
// (r10/r13/r17), prefetch depth (r12), b128 taps (r8, r18: VGPR cap + spill).
// r19: wave-private DOUBLE-BUFFERED LDS — stage pair n+1 into buf cur^1
// right after pair n's tap reads, so ds_write latency completes under the
// ~270cyc VALU ring block and pair n+1's taps issue immediately next
// iteration. Math/geometry byte-identical to r16; regs neutral (prefetch
// regs already held next pair). GUARDS: VGPR<=128 no scratch, WRITE<=50KB
// else revert to r16 and declare ceiling.

typedef float f32x2 __attribute__((ext_vector_type(2)));

struct GaussW { float w[11]; };

#define SSIM_C1 1.0e-4f
#define SSIM_C2 9.0e-4f

// ---------------- fused SSIM + L1 + laplacian kernel ------------------------
// Grid: (2 col blocks of 256, 12 row strips of 42, 32 batch) = 768 blocks.
// Block = 4 independent waves; wave wv owns 64 cols; wave-private LDS rows;
// no __syncthreads in the main loop (in-order DS pipe within a wave;
// wave_barrier() fences compiler reordering).
// Pair-row processing with LDS double-buffer: read taps of pair n from
// buf cur; stage pair n+1 into buf cur^1 BEFORE the VALU ring section;
// prefetch pair n+2 globals; cur^=1.
// Vertical gaussian: 11-slot ring; slot (row mod 11) OVERWRITTEN at k=0.
// Laplacian rides the sweep: 3-deep colsum history; strip rs owns lapl rows
// [42rs+1, 42rs+42]; strip 0 adds y=0 (reflect); strip 11 ends 510 + epi 511.
__global__ __launch_bounds__(256, 2)
void ssim_kernel(const float* __restrict__ fus, const float* __restrict__ irp,
                 const float* __restrict__ vip, const float* __restrict__ mir,
                 const float* __restrict__ mvi, float* __restrict__ ws,
                 GaussW gw)
{
    const int b    = blockIdx.z;
    const int rs   = blockIdx.y;
    const int r0   = rs * 42;
    const int tid  = threadIdx.x;
    const int wv   = tid >> 6;          // wave 0..3
    const int lane = tid & 63;
    const int c0   = blockIdx.x * 256 + wv * 64;   // wave's column base
    const int out_rows = min(42, 502 - r0);        // last strip: 40
    const int in_rows  = out_rows + 10;            // 52 or 50 (always even)
    const bool first = (rs == 0);
    const bool last  = (rs == 11);

    const size_t ib = (size_t)b * 512 * 512;
    const float* __restrict__ Fp = fus + ib;
    const float* __restrict__ Ip = irp + ib;
    const float* __restrict__ Vp = vip + ib;
    mir += ib;
    mvi += ib;

    __shared__ f32x2 srow_fi[4][2][2][80]; // [wave][buf][row-of-pair][col]
    __shared__ float srow_v [4][2][2][80];

    float w6[6];                        // gaussian symmetric: w[k]=w[10-k]
#pragma unroll
    for (int k = 0; k < 6; ++k) w6[k] = gw.w[k];

    f32x2 acc[11][4];                   // ring: [0]={hf,hi} [1]={hff,hii} [2]={hfi,hfv} [3]={hv,hvv}
#pragma unroll
    for (int s = 0; s < 11; ++s)
#pragma unroll
        for (int q = 0; q < 4; ++q) acc[s][q] = (f32x2)(0.f);

    float lssim = 0.f, l1s = 0.f, grs = 0.f;
    const int  col      = c0 + lane;
    const bool col_ok   = col <= 501;             // ssim-valid output column
    // unified halo loader: lanes 0..9 -> right halo, lane 10 -> left halo (idx 74)
    const bool is_left  = (lane == 10);
    const int  colH     = is_left ? (c0 - 1) : (c0 + 64 + lane);
    const bool halo_ok  = (lane < 10) ? (colH < 512) : (is_left && c0 > 0);
    const int  hidx     = 64 + lane;              // lane10 -> 74
    // lapl neighbor LDS index (reflect at image edges)
    const int il       = (lane == 0) ? ((c0 == 0) ? 1 : 74) : (lane - 1);
    const bool rt_edge = (lane == 63) && (c0 + 64 >= 512);  // col 511: right=reflect=left

    // laplacian history (column sums of the 2 previous rows; center of prev row)
    f32x2 csFI_1 = (f32x2)(0.f), csFI_2 = (f32x2)(0.f);
    float csV_1 = 0.f, csV_2 = 0.f;
    f32x2 cPrevFI = (f32x2)(0.f); float cPrevV = 0.f;
    // mir/mvi prefetch: mA = row r0+r-1 (for y1), mB = row r0+r (for y2)
    float mA1 = 0.f, mA2 = 0.f, mB1, mB2;

    // prologue: load pair 0 (rows r0, r0+1), stage into buf 0, then load
    // pair 1 (rows r0+2, r0+3) into the prefetch regs. mB = mir/mvi row r0.
    float arf, arg, arv, arf2 = 0.f, arg2 = 0.f, arv2 = 0.f;
    float brf, brg, brv, brf2 = 0.f, brg2 = 0.f, brv2 = 0.f;
    {
        const size_t b0 = (size_t)r0 * 512 + col;
        arf = Fp[b0]; arg = Ip[b0]; arv = Vp[b0];
        const size_t b1 = (size_t)(r0 + 1) * 512 + col;
        brf = Fp[b1]; brg = Ip[b1]; brv = Vp[b1];
        if (halo_ok) {
            const size_t h0 = (size_t)r0 * 512 + colH;
            arf2 = Fp[h0]; arg2 = Ip[h0]; arv2 = Vp[h0];
            const size_t h1 = (size_t)(r0 + 1) * 512 + colH;
            brf2 = Fp[h1]; brg2 = Ip[h1]; brv2 = Vp[h1];
        }
        mB1 = mir[b0]; mB2 = mvi[b0];
        // stage pair 0 into buf 0
        srow_fi[wv][0][0][lane] = (f32x2){arf, arg};
        srow_v [wv][0][0][lane] = arv;
        srow_fi[wv][0][1][lane] = (f32x2){brf, brg};
        srow_v [wv][0][1][lane] = brv;
        if (halo_ok) {
            srow_fi[wv][0][0][hidx] = (f32x2){arf2, arg2};
            srow_v [wv][0][0][hidx] = arv2;
            srow_fi[wv][0][1][hidx] = (f32x2){brf2, brg2};
            srow_v [wv][0][1][hidx] = brv2;
        }
        // load pair 1 (rows r0+2, r0+3; in_rows >= 50 so always valid)
        const size_t b2 = (size_t)(r0 + 2) * 512 + col;
        arf = Fp[b2]; arg = Ip[b2]; arv = Vp[b2];
        const size_t b3 = (size_t)(r0 + 3) * 512 + col;
        brf = Fp[b3]; brg = Ip[b3]; brv = Vp[b3];
        if (halo_ok) {
            const size_t h2 = (size_t)(r0 + 2) * 512 + colH;
            arf2 = Fp[h2]; arg2 = Ip[h2]; arv2 = Vp[h2];
            const size_t h3 = (size_t)(r0 + 3) * 512 + colH;
            brf2 = Fp[h3]; brg2 = Ip[h3]; brv2 = Vp[h3];
        }
    }
    __builtin_amdgcn_wave_barrier();    // staging of pair 0 ordered before reads
    int cur = 0;

#pragma unroll 1
    for (int rb = 0; rb < 66; rb += 22) {
#pragma unroll
        for (int p = 0; p < 11; ++p) {
            const int r = rb + 2 * p;             // even row of the pair
            if (r < in_rows) {                    // wave-uniform; covers r+1 too
                // ---- tap reads of pair n (buf cur) + h-sums ----
                f32x2 hfhiA = (f32x2)(0.f), hffiiA = (f32x2)(0.f);
                f32x2 hfifvA = (f32x2)(0.f), hvvvA = (f32x2)(0.f);
                f32x2 hfhiB = (f32x2)(0.f), hffiiB = (f32x2)(0.f);
                f32x2 hfifvB = (f32x2)(0.f), hvvvB = (f32x2)(0.f);
                f32x2 fi0A = (f32x2)(0.f), fi1A = (f32x2)(0.f);
                f32x2 fi0B = (f32x2)(0.f), fi1B = (f32x2)(0.f);
                float v0A = 0.f, v1A = 0.f, v0B = 0.f, v1B = 0.f;
#pragma unroll
                for (int k = 0; k < 11; ++k) {
                    const float t = w6[k < 6 ? k : 10 - k];
                    const f32x2 t2 = (f32x2){t, t};
                    const f32x2 fiA = srow_fi[wv][cur][0][lane + k];
                    const float VA  = srow_v [wv][cur][0][lane + k];
                    const f32x2 fiB = srow_fi[wv][cur][1][lane + k];
                    const float VB  = srow_v [wv][cur][1][lane + k];
                    if (k == 0) { fi0A = fiA; v0A = VA; fi0B = fiB; v0B = VB; }
                    if (k == 1) { fi1A = fiA; v1A = VA; fi1B = fiB; v1B = VB; }
                    const f32x2 tfiA = t2 * fiA;
                    hfhiA  = __builtin_elementwise_fma(t2,   fiA, hfhiA);
                    hffiiA = __builtin_elementwise_fma(tfiA, fiA, hffiiA);
                    hfifvA.x = fmaf(tfiA.x, fiA.y, hfifvA.x);
                    hfifvA.y = fmaf(tfiA.x, VA,    hfifvA.y);
                    hvvvA.x = fmaf(t,      VA, hvvvA.x);
                    hvvvA.y = fmaf(t * VA, VA, hvvvA.y);
                    const f32x2 tfiB = t2 * fiB;
                    hfhiB  = __builtin_elementwise_fma(t2,   fiB, hfhiB);
                    hffiiB = __builtin_elementwise_fma(tfiB, fiB, hffiiB);
                    hfifvB.x = fmaf(tfiB.x, fiB.y, hfifvB.x);
                    hfifvB.y = fmaf(tfiB.x, VB,    hfifvB.y);
                    hvvvB.x = fmaf(t,      VB, hvvvB.x);
                    hvvvB.y = fmaf(t * VB, VB, hvvvB.y);
                }

                // lapl column sums (left from LDS buf cur, right = k=1 tap)
                const bool lap = (r <= 43) || last;
                f32x2 csA_FI = (f32x2)(0.f), csB_FI = (f32x2)(0.f);
                float csA_V = 0.f, csB_V = 0.f;
                if (lap) {
                    const f32x2 fiLA = srow_fi[wv][cur][0][il];
                    const float vLA  = srow_v [wv][cur][0][il];
                    const f32x2 fiLB = srow_fi[wv][cur][1][il];
                    const float vLB  = srow_v [wv][cur][1][il];
                    f32x2 fiRA = fi1A; float vRA = v1A;
                    f32x2 fiRB = fi1B; float vRB = v1B;
                    if (rt_edge) { fiRA = fiLA; vRA = vLA; fiRB = fiLB; vRB = vLB; }
                    csA_FI = fiLA + fiRA + fi0A;  csA_V = vLA + vRA + v0A;
                    csB_FI = fiLB + fiRB + fi0B;  csB_V = vLB + vRB + v0B;
                }
                __builtin_amdgcn_wave_barrier();  // reads(cur) before writes below

                // ---- stage pair n+1 into buf cur^1 (write latency hides
                //      under the VALU ring section below) ----
                if (r + 2 < in_rows) {
                    srow_fi[wv][cur ^ 1][0][lane] = (f32x2){arf, arg};
                    srow_v [wv][cur ^ 1][0][lane] = arv;
                    srow_fi[wv][cur ^ 1][1][lane] = (f32x2){brf, brg};
                    srow_v [wv][cur ^ 1][1][lane] = brv;
                    if (halo_ok) {
                        srow_fi[wv][cur ^ 1][0][hidx] = (f32x2){arf2, arg2};
                        srow_v [wv][cur ^ 1][0][hidx] = arv2;
                        srow_fi[wv][cur ^ 1][1][hidx] = (f32x2){brf2, brg2};
                        srow_v [wv][cur ^ 1][1][hidx] = brv2;
                    }
                }
                __builtin_amdgcn_wave_barrier();

                // ---- prefetch pair n+2 globals ----
                if (r + 4 < in_rows) {
                    const size_t bA = (size_t)(r0 + r + 4) * 512 + col;
                    arf = Fp[bA]; arg = Ip[bA]; arv = Vp[bA];
                    const size_t bB = (size_t)(r0 + r + 5) * 512 + col;
                    brf = Fp[bB]; brg = Ip[bB]; brv = Vp[bB];
                    if (halo_ok) {
                        const size_t hA = (size_t)(r0 + r + 4) * 512 + colH;
                        arf2 = Fp[hA]; arg2 = Ip[hA]; arv2 = Vp[hA];
                        const size_t hB = (size_t)(r0 + r + 5) * 512 + colH;
                        brf2 = Fp[hB]; brg2 = Ip[hB]; brv2 = Vp[hB];
                    }
                }

                // ---- row r: ring update then finalize output r-10 ----
                {
                    const f32x2 w02 = (f32x2){w6[0], w6[0]};
                    acc[(2*p) % 11][0] = w02 * hfhiA;
                    acc[(2*p) % 11][1] = w02 * hffiiA;
                    acc[(2*p) % 11][2] = w02 * hfifvA;
                    acc[(2*p) % 11][3] = w02 * hvvvA;
                }
#pragma unroll
                for (int k = 1; k < 11; ++k) {
                    const int s = (2*p - k + 22) % 11;   // compile-time
                    const float t = w6[k < 6 ? k : 10 - k];
                    const f32x2 t2 = (f32x2){t, t};
                    acc[s][0] = __builtin_elementwise_fma(t2, hfhiA,  acc[s][0]);
                    acc[s][1] = __builtin_elementwise_fma(t2, hffiiA, acc[s][1]);
                    acc[s][2] = __builtin_elementwise_fma(t2, hfifvA, acc[s][2]);
                    acc[s][3] = __builtin_elementwise_fma(t2, hvvvA,  acc[s][3]);
                }
                if (r >= 10) {
                    const int s = (2*p + 1) % 11;        // compile-time
                    const float mu1 = acc[s][0].x, mu2 = acc[s][0].y, mu3 = acc[s][3].x;
                    const float eff = acc[s][1].x, eii = acc[s][1].y, evv = acc[s][3].y;
                    const float efi = acc[s][2].x, efv = acc[s][2].y;
                    const float mu1sq = mu1*mu1, mu2sq = mu2*mu2, mu3sq = mu3*mu3;
                    const float mu12 = mu1*mu2, mu13 = mu1*mu3;
                    const float sf  = eff - mu1sq;
                    const float si  = eii - mu2sq;
                    const float sv  = evv - mu3sq;
                    const float s12 = efi - mu12;
                    const float s13 = efv - mu13;
                    const float n1 = (2.f*mu12 + SSIM_C1) * (2.f*s12 + SSIM_C2);
                    const float d1 = (mu1sq + mu2sq + SSIM_C1) * (sf + si + SSIM_C2);
                    const float n2 = (2.f*mu13 + SSIM_C1) * (2.f*s13 + SSIM_C2);
                    const float d2 = (mu1sq + mu3sq + SSIM_C1) * (sf + sv + SSIM_C2);
                    const float q1 = __builtin_amdgcn_rcpf(d1);   // ~2^-22 vs 6.6e-2 tol
                    const float q2 = __builtin_amdgcn_rcpf(d2);
                    if (col_ok) lssim += fmaf(n1, q1, n2 * q2);
                }
                // ---- row r+1: ring update then finalize output r-9 ----
                {
                    const f32x2 w02 = (f32x2){w6[0], w6[0]};
                    acc[(2*p + 1) % 11][0] = w02 * hfhiB;
                    acc[(2*p + 1) % 11][1] = w02 * hffiiB;
                    acc[(2*p + 1) % 11][2] = w02 * hfifvB;
                    acc[(2*p + 1) % 11][3] = w02 * hvvvB;
                }
#pragma unroll
                for (int k = 1; k < 11; ++k) {
                    const int s = (2*p + 1 - k + 22) % 11;   // compile-time
                    const float t = w6[k < 6 ? k : 10 - k];
                    const f32x2 t2 = (f32x2){t, t};
                    acc[s][0] = __builtin_elementwise_fma(t2, hfhiB,  acc[s][0]);
                    acc[s][1] = __builtin_elementwise_fma(t2, hffiiB, acc[s][1]);
                    acc[s][2] = __builtin_elementwise_fma(t2, hfifvB, acc[s][2]);
                    acc[s][3] = __builtin_elementwise_fma(t2, hvvvB,  acc[s][3]);
                }
                if (r >= 10) {
                    const int s = (2*p + 2) % 11;        // compile-time
                    const float mu1 = acc[s][0].x, mu2 = acc[s][0].y, mu3 = acc[s][3].x;
                    const float eff = acc[s][1].x, eii = acc[s][1].y, evv = acc[s][3].y;
                    const float efi = acc[s][2].x, efv = acc[s][2].y;
                    const float mu1sq = mu1*mu1, mu2sq = mu2*mu2, mu3sq = mu3*mu3;
                    const float mu12 = mu1*mu2, mu13 = mu1*mu3;
                    const float sf  = eff - mu1sq;
                    const float si  = eii - mu2sq;
                    const float sv  = evv - mu3sq;
                    const float s12 = efi - mu12;
                    const float s13 = efv - mu13;
                    const float n1 = (2.f*mu12 + SSIM_C1) * (2.f*s12 + SSIM_C2);
                    const float d1 = (mu1sq + mu2sq + SSIM_C1) * (sf + si + SSIM_C2);
                    const float n2 = (2.f*mu13 + SSIM_C1) * (2.f*s13 + SSIM_C2);
                    const float d2 = (mu1sq + mu3sq + SSIM_C1) * (sf + sv + SSIM_C2);
                    const float q1 = __builtin_amdgcn_rcpf(d1);
                    const float q2 = __builtin_amdgcn_rcpf(d2);
                    if (col_ok) lssim += fmaf(n1, q1, n2 * q2);
                }

                // ---- laplacian + l1 emissions (16x-unscaled lapl) ----
                if (lap) {
                    if (r >= 2) {
                        // y1 = r0+r-1: rows r-2, r-1, r; center row r-1
                        const f32x2 sFI = csFI_2 + csFI_1 + csA_FI;
                        const float sV  = csV_2 + csV_1 + csA_V;
                        const f32x2 lFI = __builtin_elementwise_fma(
                                             (f32x2){-9.f,-9.f}, cPrevFI, sFI);
                        const float lV  = fmaf(-9.f, cPrevV, sV);
                        grs += fabsf(fmaxf(fabsf(lFI.y), fabsf(lV)) - fabsf(lFI.x));
                        l1s += fabsf(fmaxf(mA1, mA2) - cPrevFI.x);
                        // y2 = r0+r: rows r-1, r, r+1; center row r
                        const f32x2 sFI2 = csFI_1 + csA_FI + csB_FI;
                        const float sV2  = csV_1 + csA_V + csB_V;
                        const f32x2 lFI2 = __builtin_elementwise_fma(
                                             (f32x2){-9.f,-9.f}, fi0A, sFI2);
                        const float lV2  = fmaf(-9.f, v0A, sV2);
                        grs += fabsf(fmaxf(fabsf(lFI2.y), fabsf(lV2)) - fabsf(lFI2.x));
                        l1s += fabsf(fmaxf(mB1, mB2) - fi0A.x);
                    }
                    if (first && r == 0) {
                        // y = 0: rows reflect(-1)=1, 0, 1; center row 0
                        const f32x2 sFI = csA_FI + csB_FI + csB_FI;
                        const float sV  = csA_V + csB_V + csB_V;
                        const f32x2 lFI = __builtin_elementwise_fma(
                                             (f32x2){-9.f,-9.f}, fi0A, sFI);
                        const float lV  = fmaf(-9.f, v0A, sV);
                        grs += fabsf(fmaxf(fabsf(lFI.y), fabsf(lV)) - fabsf(lFI.x));
                        l1s += fabsf(fmaxf(mB1, mB2) - fi0A.x);
                    }
                    // shift history by 2 rows; prefetch m rows for next pair
                    csFI_2 = csA_FI; csFI_1 = csB_FI;
                    csV_2  = csA_V;  csV_1  = csB_V;
                    cPrevFI = fi0B;  cPrevV = v0B;
                    if (r + 2 < in_rows) {
                        const int yA = min(r0 + r + 1, 511);
                        const int yB = min(r0 + r + 2, 511);
                        const size_t bmA = (size_t)yA * 512 + col;
                        const size_t bmB = (size_t)yB * 512 + col;
                        mA1 = mir[bmA]; mA2 = mvi[bmA];
                        mB1 = mir[bmB]; mB2 = mvi[bmB];
                    }
                }
                cur ^= 1;
            }
        }
    }

    // epilogue: last strip handles row 511 (reflect row 512 -> 510)
    if (last) {
        const size_t bm = (size_t)511 * 512 + col;
        const float m1e = mir[bm], m2e = mvi[bm];
        const f32x2 sFI = csFI_2 + csFI_2 + csFI_1;
        const float sV  = csV_2 + csV_2 + csV_1;
        const f32x2 lFI = __builtin_elementwise_fma((f32x2){-9.f,-9.f}, cPrevFI, sFI);
        const float lV  = fmaf(-9.f, cPrevV, sV);
        grs += fabsf(fmaxf(fabsf(lFI.y), fabsf(lV)) - fabsf(lFI.x));
        l1s += fabsf(fmaxf(m1e, m2e) - cPrevFI.x);
    }

    // cross-wave block reduction -> three partial writes (no atomics)
#pragma unroll
    for (int off = 32; off > 0; off >>= 1) {
        lssim += __shfl_down(lssim, off);
        l1s   += __shfl_down(l1s, off);
        grs   += __shfl_down(grs, off);
    }
    __shared__ float red[12];
    if (lane == 0) { red[wv] = lssim; red[4 + wv] = l1s; red[8 + wv] = grs; }
    __syncthreads();
    if (tid == 0) {
        const int blk = blockIdx.x + 2 * (blockIdx.y + 12 * blockIdx.z); // 0..767
        ws[blk]        = red[0] + red[1] + red[2] + red[3];
        ws[768 + blk]  = red[4] + red[5] + red[6] + red[7];
        ws[1536 + blk] = (red[8] + red[9] + red[10] + red[11]) * 0.0625f; // /16
    }
}

// ---------------- final combine: reduce all partials ------------------------
__global__ void final_kernel(const float* __restrict__ ws, float* __restrict__ out)
{
    const int tid = threadIdx.x;
    float s0 = 0.f, s1 = 0.f, s2 = 0.f;
#pragma unroll
    for (int i = tid; i < 768; i += 256) {
        s0 += ws[i];
        s1 += ws[768 + i];
        s2 += ws[1536 + i];
    }
#pragma unroll
    for (int off = 32; off > 0; off >>= 1) {
        s0 += __shfl_down(s0, off);
        s1 += __shfl_down(s1, off);
        s2 += __shfl_down(s2, off);
    }
    __shared__ float red[12];
    if ((tid & 63) == 0) {
        red[tid >> 6] = s0; red[4 + (tid >> 6)] = s1; red[8 + (tid >> 6)] = s2;
    }
    __syncthreads();
    if (tid == 0) {
        const float ssim_sum = red[0] + red[1] + red[2] + red[3];
        const float l1_sum   = red[4] + red[5] + red[6] + red[7];
        const float gr_sum   = red[8] + red[9] + red[10] + red[11];
        const float ms = 2.f - ssim_sum / 8064128.f;   // 32*502*502
        const float l1 = l1_sum / 8388608.f;           // 32*512*512
        const float gr = gr_sum / 8388608.f;
        out[0] = ms + l1 + 10.f * gr;
    }
}

extern "C" void kernel_launch(void* const* d_in, const int* in_sizes, int n_in,
                              void* d_out, int out_size, void* d_ws, size_t ws_size,
                              hipStream_t stream)
{
    const float* fus = (const float*)d_in[0];
    const float* irp = (const float*)d_in[1];
    const float* vip = (const float*)d_in[2];
    const float* mir = (const float*)d_in[3];
    const float* mvi = (const float*)d_in[4];
    float* out = (float*)d_out;
    float* ws  = (float*)d_ws;

    // gaussian window (matches np: f64 normalize, cast to f32)
    GaussW gw;
    double g[11], s = 0.0;
    for (int i = 0; i < 11; ++i) {
        const double d = (double)i - 5.0;
        g[i] = std::exp(-(d * d) / (2.0 * 1.5 * 1.5));
        s += g[i];
    }
    for (int i = 0; i < 11; ++i) gw.w[i] = (float)(g[i] / s);

    ssim_kernel<<<dim3(2, 12, 32), 256, 0, stream>>>(fus, irp, vip, mir, mvi,
                                                     ws, gw);
    final_kernel<<<1, 256, 0, stream>>>(ws, out);
}

// Round 20
// 89.913 us; speedup vs baseline: 1.1332x; 1.0194x over previous
//
#include <hip/hip_runtime.h>
#include <cmath>

// FusionLoss = ms_ssim(fus,ir)+ms_ssim(fus,vi) + l1(max(map_ir,map_vi),fus)
//            + 10*mean(|max(|lap ir|,|lap vi|) - |lap fus||)
// Inputs: im_fus, im_ir, im_vi, map_ir, map_vi  each [32,1,512,512] fp32.
//
// d_ws layout (floats): [0..768) ssim | [768..1536) l1 | [1536..2304) grad
//
// FINAL (r20 = r16 revert, measured best 90.0us).
// Journal: r2 atomics->partials (306->126). r9 pk-f32 (110.9). r14 lapl
// rides ssim pipeline (103.8). r15 DS/reg diet (96.5). r16 pair-row (90.0,
// BEST). Refuted levers: occupancy (r10/r13/r17 — 12 waves/CU is hard for
// this register footprint), prefetch depth (r12), b128 taps (r8/r18 quad
// spill), LDS double-buffer (r19), side-by-side fusion (r11). Kernel is
// dependency-latency bound: DS ~45us busy + VALU ~43us busy, ~50% each,
// at the 3-blocks/CU residency ceiling.

typedef float f32x2 __attribute__((ext_vector_type(2)));

struct GaussW { float w[11]; };

#define SSIM_C1 1.0e-4f
#define SSIM_C2 9.0e-4f

// ---------------- fused SSIM + L1 + laplacian kernel ------------------------
// Grid: (2 col blocks of 256, 12 row strips of 42, 32 batch) = 768 blocks.
// Block = 4 independent waves; wave wv owns 64 cols; wave-private LDS rows;
// no __syncthreads in the main loop (in-order DS pipe within a wave;
// wave_barrier() fences compiler reordering).
// Pair-row processing: rows r,r+1 staged together; 44 tap reads issued as
// one stream (one exposed-latency window per PAIR); two h-sum chains.
// Vertical gaussian: 11-slot ring; slot (row mod 11) OVERWRITTEN at k=0.
// Laplacian rides the sweep: 3-deep colsum history; strip rs owns lapl rows
// [42rs+1, 42rs+42]; strip 0 adds y=0 (reflect); strip 11 ends 510 + epi 511.
__global__ __launch_bounds__(256, 2)
void ssim_kernel(const float* __restrict__ fus, const float* __restrict__ irp,
                 const float* __restrict__ vip, const float* __restrict__ mir,
                 const float* __restrict__ mvi, float* __restrict__ ws,
                 GaussW gw)
{
    const int b    = blockIdx.z;
    const int rs   = blockIdx.y;
    const int r0   = rs * 42;
    const int tid  = threadIdx.x;
    const int wv   = tid >> 6;          // wave 0..3
    const int lane = tid & 63;
    const int c0   = blockIdx.x * 256 + wv * 64;   // wave's column base
    const int out_rows = min(42, 502 - r0);        // last strip: 40
    const int in_rows  = out_rows + 10;            // 52 or 50 (always even)
    const bool first = (rs == 0);
    const bool last  = (rs == 11);

    const size_t ib = (size_t)b * 512 * 512;
    const float* __restrict__ Fp = fus + ib;
    const float* __restrict__ Ip = irp + ib;
    const float* __restrict__ Vp = vip + ib;
    mir += ib;
    mvi += ib;

    __shared__ f32x2 srow_fi[4][2][80]; // [wave][row-of-pair][col]
    __shared__ float srow_v [4][2][80];

    float w6[6];                        // gaussian symmetric: w[k]=w[10-k]
#pragma unroll
    for (int k = 0; k < 6; ++k) w6[k] = gw.w[k];

    f32x2 acc[11][4];                   // ring: [0]={hf,hi} [1]={hff,hii} [2]={hfi,hfv} [3]={hv,hvv}
#pragma unroll
    for (int s = 0; s < 11; ++s)
#pragma unroll
        for (int q = 0; q < 4; ++q) acc[s][q] = (f32x2)(0.f);

    float lssim = 0.f, l1s = 0.f, grs = 0.f;
    const int  col      = c0 + lane;
    const bool col_ok   = col <= 501;             // ssim-valid output column
    // unified halo loader: lanes 0..9 -> right halo, lane 10 -> left halo (idx 74)
    const bool is_left  = (lane == 10);
    const int  colH     = is_left ? (c0 - 1) : (c0 + 64 + lane);
    const bool halo_ok  = (lane < 10) ? (colH < 512) : (is_left && c0 > 0);
    const int  hidx     = 64 + lane;              // lane10 -> 74
    // lapl neighbor LDS index (reflect at image edges)
    const int il       = (lane == 0) ? ((c0 == 0) ? 1 : 74) : (lane - 1);
    const bool rt_edge = (lane == 63) && (c0 + 64 >= 512);  // col 511: right=reflect=left

    // laplacian history (column sums of the 2 previous rows; center of prev row)
    f32x2 csFI_1 = (f32x2)(0.f), csFI_2 = (f32x2)(0.f);
    float csV_1 = 0.f, csV_2 = 0.f;
    f32x2 cPrevFI = (f32x2)(0.f); float cPrevV = 0.f;
    // mir/mvi prefetch: mA = row r0+r-1 (for y1), mB = row r0+r (for y2)
    float mA1 = 0.f, mA2 = 0.f, mB1, mB2;

    // prologue: prefetch rows 0 (A) and 1 (B), main + unified halo; mB = row r0
    float arf, arg, arv, arf2 = 0.f, arg2 = 0.f, arv2 = 0.f;
    float brf, brg, brv, brf2 = 0.f, brg2 = 0.f, brv2 = 0.f;
    {
        const size_t b0 = (size_t)r0 * 512 + col;
        arf = Fp[b0]; arg = Ip[b0]; arv = Vp[b0];
        const size_t b1 = (size_t)(r0 + 1) * 512 + col;
        brf = Fp[b1]; brg = Ip[b1]; brv = Vp[b1];
        if (halo_ok) {
            const size_t h0 = (size_t)r0 * 512 + colH;
            arf2 = Fp[h0]; arg2 = Ip[h0]; arv2 = Vp[h0];
            const size_t h1 = (size_t)(r0 + 1) * 512 + colH;
            brf2 = Fp[h1]; brg2 = Ip[h1]; brv2 = Vp[h1];
        }
        mB1 = mir[b0]; mB2 = mvi[b0];
    }

#pragma unroll 1
    for (int rb = 0; rb < 66; rb += 22) {
#pragma unroll
        for (int p = 0; p < 11; ++p) {
            const int r = rb + 2 * p;             // even row of the pair
            if (r < in_rows) {                    // wave-uniform; covers r+1 too
                // stage both rows (b64 pair + b32 V each, + unified halo)
                srow_fi[wv][0][lane] = (f32x2){arf, arg};
                srow_v [wv][0][lane] = arv;
                srow_fi[wv][1][lane] = (f32x2){brf, brg};
                srow_v [wv][1][lane] = brv;
                if (halo_ok) {
                    srow_fi[wv][0][hidx] = (f32x2){arf2, arg2};
                    srow_v [wv][0][hidx] = arv2;
                    srow_fi[wv][1][hidx] = (f32x2){brf2, brg2};
                    srow_v [wv][1][hidx] = brv2;
                }
                __builtin_amdgcn_wave_barrier();  // fence write->read order

                // prefetch rows r+2 (A) and r+3 (B); consumed next pair
                if (r + 2 < in_rows) {
                    const size_t bA = (size_t)(r0 + r + 2) * 512 + col;
                    arf = Fp[bA]; arg = Ip[bA]; arv = Vp[bA];
                    const size_t bB = (size_t)(r0 + r + 3) * 512 + col;
                    brf = Fp[bB]; brg = Ip[bB]; brv = Vp[bB];
                    if (halo_ok) {
                        const size_t hA = (size_t)(r0 + r + 2) * 512 + colH;
                        arf2 = Fp[hA]; arg2 = Ip[hA]; arv2 = Vp[hA];
                        const size_t hB = (size_t)(r0 + r + 3) * 512 + colH;
                        brf2 = Fp[hB]; brg2 = Ip[hB]; brv2 = Vp[hB];
                    }
                }

                // horizontal gaussian sums for BOTH rows (one read stream,
                // two independent dependency chains); capture k=0 (center)
                // and k=1 (right neighbor) taps for the laplacian.
                f32x2 hfhiA = (f32x2)(0.f), hffiiA = (f32x2)(0.f);
                f32x2 hfifvA = (f32x2)(0.f), hvvvA = (f32x2)(0.f);
                f32x2 hfhiB = (f32x2)(0.f), hffiiB = (f32x2)(0.f);
                f32x2 hfifvB = (f32x2)(0.f), hvvvB = (f32x2)(0.f);
                f32x2 fi0A = (f32x2)(0.f), fi1A = (f32x2)(0.f);
                f32x2 fi0B = (f32x2)(0.f), fi1B = (f32x2)(0.f);
                float v0A = 0.f, v1A = 0.f, v0B = 0.f, v1B = 0.f;
#pragma unroll
                for (int k = 0; k < 11; ++k) {
                    const float t = w6[k < 6 ? k : 10 - k];
                    const f32x2 t2 = (f32x2){t, t};
                    const f32x2 fiA = srow_fi[wv][0][lane + k];
                    const float VA  = srow_v [wv][0][lane + k];
                    const f32x2 fiB = srow_fi[wv][1][lane + k];
                    const float VB  = srow_v [wv][1][lane + k];
                    if (k == 0) { fi0A = fiA; v0A = VA; fi0B = fiB; v0B = VB; }
                    if (k == 1) { fi1A = fiA; v1A = VA; fi1B = fiB; v1B = VB; }
                    const f32x2 tfiA = t2 * fiA;
                    hfhiA  = __builtin_elementwise_fma(t2,   fiA, hfhiA);
                    hffiiA = __builtin_elementwise_fma(tfiA, fiA, hffiiA);
                    hfifvA.x = fmaf(tfiA.x, fiA.y, hfifvA.x);
                    hfifvA.y = fmaf(tfiA.x, VA,    hfifvA.y);
                    hvvvA.x = fmaf(t,      VA, hvvvA.x);
                    hvvvA.y = fmaf(t * VA, VA, hvvvA.y);
                    const f32x2 tfiB = t2 * fiB;
                    hfhiB  = __builtin_elementwise_fma(t2,   fiB, hfhiB);
                    hffiiB = __builtin_elementwise_fma(tfiB, fiB, hffiiB);
                    hfifvB.x = fmaf(tfiB.x, fiB.y, hfifvB.x);
                    hfifvB.y = fmaf(tfiB.x, VB,    hfifvB.y);
                    hvvvB.x = fmaf(t,      VB, hvvvB.x);
                    hvvvB.y = fmaf(t * VB, VB, hvvvB.y);
                }

                // lapl column sums for both rows (left from LDS, right = k=1 tap)
                const bool lap = (r <= 43) || last;
                f32x2 csA_FI = (f32x2)(0.f), csB_FI = (f32x2)(0.f);
                float csA_V = 0.f, csB_V = 0.f;
                if (lap) {
                    const f32x2 fiLA = srow_fi[wv][0][il];
                    const float vLA  = srow_v [wv][0][il];
                    const f32x2 fiLB = srow_fi[wv][1][il];
                    const float vLB  = srow_v [wv][1][il];
                    f32x2 fiRA = fi1A; float vRA = v1A;
                    f32x2 fiRB = fi1B; float vRB = v1B;
                    if (rt_edge) { fiRA = fiLA; vRA = vLA; fiRB = fiLB; vRB = vLB; }
                    csA_FI = fiLA + fiRA + fi0A;  csA_V = vLA + vRA + v0A;
                    csB_FI = fiLB + fiRB + fi0B;  csB_V = vLB + vRB + v0B;
                }
                __builtin_amdgcn_wave_barrier();  // fence read->next-write

                // ---- row r: ring update then finalize output r-10 ----
                {
                    const f32x2 w02 = (f32x2){w6[0], w6[0]};
                    acc[(2*p) % 11][0] = w02 * hfhiA;
                    acc[(2*p) % 11][1] = w02 * hffiiA;
                    acc[(2*p) % 11][2] = w02 * hfifvA;
                    acc[(2*p) % 11][3] = w02 * hvvvA;
                }
#pragma unroll
                for (int k = 1; k < 11; ++k) {
                    const int s = (2*p - k + 22) % 11;   // compile-time
                    const float t = w6[k < 6 ? k : 10 - k];
                    const f32x2 t2 = (f32x2){t, t};
                    acc[s][0] = __builtin_elementwise_fma(t2, hfhiA,  acc[s][0]);
                    acc[s][1] = __builtin_elementwise_fma(t2, hffiiA, acc[s][1]);
                    acc[s][2] = __builtin_elementwise_fma(t2, hfifvA, acc[s][2]);
                    acc[s][3] = __builtin_elementwise_fma(t2, hvvvA,  acc[s][3]);
                }
                if (r >= 10) {
                    const int s = (2*p + 1) % 11;        // compile-time
                    const float mu1 = acc[s][0].x, mu2 = acc[s][0].y, mu3 = acc[s][3].x;
                    const float eff = acc[s][1].x, eii = acc[s][1].y, evv = acc[s][3].y;
                    const float efi = acc[s][2].x, efv = acc[s][2].y;
                    const float mu1sq = mu1*mu1, mu2sq = mu2*mu2, mu3sq = mu3*mu3;
                    const float mu12 = mu1*mu2, mu13 = mu1*mu3;
                    const float sf  = eff - mu1sq;
                    const float si  = eii - mu2sq;
                    const float sv  = evv - mu3sq;
                    const float s12 = efi - mu12;
                    const float s13 = efv - mu13;
                    const float n1 = (2.f*mu12 + SSIM_C1) * (2.f*s12 + SSIM_C2);
                    const float d1 = (mu1sq + mu2sq + SSIM_C1) * (sf + si + SSIM_C2);
                    const float n2 = (2.f*mu13 + SSIM_C1) * (2.f*s13 + SSIM_C2);
                    const float d2 = (mu1sq + mu3sq + SSIM_C1) * (sf + sv + SSIM_C2);
                    const float q1 = __builtin_amdgcn_rcpf(d1);   // ~2^-22 vs 6.6e-2 tol
                    const float q2 = __builtin_amdgcn_rcpf(d2);
                    if (col_ok) lssim += fmaf(n1, q1, n2 * q2);
                }
                // ---- row r+1: ring update then finalize output r-9 ----
                {
                    const f32x2 w02 = (f32x2){w6[0], w6[0]};
                    acc[(2*p + 1) % 11][0] = w02 * hfhiB;
                    acc[(2*p + 1) % 11][1] = w02 * hffiiB;
                    acc[(2*p + 1) % 11][2] = w02 * hfifvB;
                    acc[(2*p + 1) % 11][3] = w02 * hvvvB;
                }
#pragma unroll
                for (int k = 1; k < 11; ++k) {
                    const int s = (2*p + 1 - k + 22) % 11;   // compile-time
                    const float t = w6[k < 6 ? k : 10 - k];
                    const f32x2 t2 = (f32x2){t, t};
                    acc[s][0] = __builtin_elementwise_fma(t2, hfhiB,  acc[s][0]);
                    acc[s][1] = __builtin_elementwise_fma(t2, hffiiB, acc[s][1]);
                    acc[s][2] = __builtin_elementwise_fma(t2, hfifvB, acc[s][2]);
                    acc[s][3] = __builtin_elementwise_fma(t2, hvvvB,  acc[s][3]);
                }
                if (r >= 10) {
                    const int s = (2*p + 2) % 11;        // compile-time
                    const float mu1 = acc[s][0].x, mu2 = acc[s][0].y, mu3 = acc[s][3].x;
                    const float eff = acc[s][1].x, eii = acc[s][1].y, evv = acc[s][3].y;
                    const float efi = acc[s][2].x, efv = acc[s][2].y;
                    const float mu1sq = mu1*mu1, mu2sq = mu2*mu2, mu3sq = mu3*mu3;
                    const float mu12 = mu1*mu2, mu13 = mu1*mu3;
                    const float sf  = eff - mu1sq;
                    const float si  = eii - mu2sq;
                    const float sv  = evv - mu3sq;
                    const float s12 = efi - mu12;
                    const float s13 = efv - mu13;
                    const float n1 = (2.f*mu12 + SSIM_C1) * (2.f*s12 + SSIM_C2);
                    const float d1 = (mu1sq + mu2sq + SSIM_C1) * (sf + si + SSIM_C2);
                    const float n2 = (2.f*mu13 + SSIM_C1) * (2.f*s13 + SSIM_C2);
                    const float d2 = (mu1sq + mu3sq + SSIM_C1) * (sf + sv + SSIM_C2);
                    const float q1 = __builtin_amdgcn_rcpf(d1);
                    const float q2 = __builtin_amdgcn_rcpf(d2);
                    if (col_ok) lssim += fmaf(n1, q1, n2 * q2);
                }

                // ---- laplacian + l1 emissions (16x-unscaled lapl) ----
                if (lap) {
                    if (r >= 2) {
                        // y1 = r0+r-1: rows r-2, r-1, r; center row r-1
                        const f32x2 sFI = csFI_2 + csFI_1 + csA_FI;
                        const float sV  = csV_2 + csV_1 + csA_V;
                        const f32x2 lFI = __builtin_elementwise_fma(
                                             (f32x2){-9.f,-9.f}, cPrevFI, sFI);
                        const float lV  = fmaf(-9.f, cPrevV, sV);
                        grs += fabsf(fmaxf(fabsf(lFI.y), fabsf(lV)) - fabsf(lFI.x));
                        l1s += fabsf(fmaxf(mA1, mA2) - cPrevFI.x);
                        // y2 = r0+r: rows r-1, r, r+1; center row r
                        const f32x2 sFI2 = csFI_1 + csA_FI + csB_FI;
                        const float sV2  = csV_1 + csA_V + csB_V;
                        const f32x2 lFI2 = __builtin_elementwise_fma(
                                             (f32x2){-9.f,-9.f}, fi0A, sFI2);
                        const float lV2  = fmaf(-9.f, v0A, sV2);
                        grs += fabsf(fmaxf(fabsf(lFI2.y), fabsf(lV2)) - fabsf(lFI2.x));
                        l1s += fabsf(fmaxf(mB1, mB2) - fi0A.x);
                    }
                    if (first && r == 0) {
                        // y = 0: rows reflect(-1)=1, 0, 1; center row 0
                        const f32x2 sFI = csA_FI + csB_FI + csB_FI;
                        const float sV  = csA_V + csB_V + csB_V;
                        const f32x2 lFI = __builtin_elementwise_fma(
                                             (f32x2){-9.f,-9.f}, fi0A, sFI);
                        const float lV  = fmaf(-9.f, v0A, sV);
                        grs += fabsf(fmaxf(fabsf(lFI.y), fabsf(lV)) - fabsf(lFI.x));
                        l1s += fabsf(fmaxf(mB1, mB2) - fi0A.x);
                    }
                    // shift history by 2 rows; prefetch m rows for next pair
                    csFI_2 = csA_FI; csFI_1 = csB_FI;
                    csV_2  = csA_V;  csV_1  = csB_V;
                    cPrevFI = fi0B;  cPrevV = v0B;
                    if (r + 2 < in_rows) {
                        const int yA = min(r0 + r + 1, 511);
                        const int yB = min(r0 + r + 2, 511);
                        const size_t bmA = (size_t)yA * 512 + col;
                        const size_t bmB = (size_t)yB * 512 + col;
                        mA1 = mir[bmA]; mA2 = mvi[bmA];
                        mB1 = mir[bmB]; mB2 = mvi[bmB];
                    }
                }
            }
        }
    }

    // epilogue: last strip handles row 511 (reflect row 512 -> 510)
    if (last) {
        const size_t bm = (size_t)511 * 512 + col;
        const float m1e = mir[bm], m2e = mvi[bm];
        const f32x2 sFI = csFI_2 + csFI_2 + csFI_1;
        const float sV  = csV_2 + csV_2 + csV_1;
        const f32x2 lFI = __builtin_elementwise_fma((f32x2){-9.f,-9.f}, cPrevFI, sFI);
        const float lV  = fmaf(-9.f, cPrevV, sV);
        grs += fabsf(fmaxf(fabsf(lFI.y), fabsf(lV)) - fabsf(lFI.x));
        l1s += fabsf(fmaxf(m1e, m2e) - cPrevFI.x);
    }

    // cross-wave block reduction -> three partial writes (no atomics)
#pragma unroll
    for (int off = 32; off > 0; off >>= 1) {
        lssim += __shfl_down(lssim, off);
        l1s   += __shfl_down(l1s, off);
        grs   += __shfl_down(grs, off);
    }
    __shared__ float red[12];
    if (lane == 0) { red[wv] = lssim; red[4 + wv] = l1s; red[8 + wv] = grs; }
    __syncthreads();
    if (tid == 0) {
        const int blk = blockIdx.x + 2 * (blockIdx.y + 12 * blockIdx.z); // 0..767
        ws[blk]        = red[0] + red[1] + red[2] + red[3];
        ws[768 + blk]  = red[4] + red[5] + red[6] + red[7];
        ws[1536 + blk] = (red[8] + red[9] + red[10] + red[11]) * 0.0625f; // /16
    }
}

// ---------------- final combine: reduce all partials ------------------------
__global__ void final_kernel(const float* __restrict__ ws, float* __restrict__ out)
{
    const int tid = threadIdx.x;
    float s0 = 0.f, s1 = 0.f, s2 = 0.f;
#pragma unroll
    for (int i = tid; i < 768; i += 256) {
        s0 += ws[i];
        s1 += ws[768 + i];
        s2 += ws[1536 + i];
    }
#pragma unroll
    for (int off = 32; off > 0; off >>= 1) {
        s0 += __shfl_down(s0, off);
        s1 += __shfl_down(s1, off);
        s2 += __shfl_down(s2, off);
    }
    __shared__ float red[12];
    if ((tid & 63) == 0) {
        red[tid >> 6] = s0; red[4 + (tid >> 6)] = s1; red[8 + (tid >> 6)] = s2;
    }
    __syncthreads();
    if (tid == 0) {
        const float ssim_sum = red[0] + red[1] + red[2] + red[3];
        const float l1_sum   = red[4] + red[5] + red[6] + red[7];
        const float gr_sum   = red[8] + red[9] + red[10] + red[11];
        const float ms = 2.f - ssim_sum / 8064128.f;   // 32*502*502
        const float l1 = l1_sum / 8388608.f;           // 32*512*512
        const float gr = gr_sum / 8388608.f;
        out[0] = ms + l1 + 10.f * gr;
    }
}

extern "C" void kernel_launch(void* const* d_in, const int* in_sizes, int n_in,
                              void* d_out, int out_size, void* d_ws, size_t ws_size,
                              hipStream_t stream)
{
    const float* fus = (const float*)d_in[0];
    const float* irp = (const float*)d_in[1];
    const float* vip = (const float*)d_in[2];
    const float* mir = (const float*)d_in[3];
    const float* mvi = (const float*)d_in[4];
    float* out = (float*)d_out;
    float* ws  = (float*)d_ws;

    // gaussian window (matches np: f64 normalize, cast to f32)
    GaussW gw;
    double g[11], s = 0.0;
    for (int i = 0; i < 11; ++i) {
        const double d = (double)i - 5.0;
        g[i] = std::exp(-(d * d) / (2.0 * 1.5 * 1.5));
        s += g[i];
    }
    for (int i = 0; i < 11; ++i) gw.w[i] = (float)(g[i] / s);

    ssim_kernel<<<dim3(2, 12, 32), 256, 0, stream>>>(fus, irp, vip, mir, mvi,
                                                     ws, gw);
    final_kernel<<<1, 256, 0, stream>>>(ws, out);
}